// Round 2
// baseline (87.461 us; speedup 1.0000x reference)
//
#include <hip/hip_runtime.h>

// LatticeSnake: B=32, L=512, W=9.
// One block per group of G=4 consecutive windows of one batch. Consecutive
// window centers differ by <=2 (doubled coords), so the union of 4 windows
// fits in a 15^3 box (13.5 KB LDS). Scatter all M=1023 snake points once
// into the box, then emit the 4 windows' tiles as one flat float4 stream.
//
// R2 changes vs R1 (512t / G=8 / 48.7KB box, ~no gain over baseline):
//  - G=8 -> G=4: LDS 48.7 -> 13.5 KB. At G=8 LDS capped residency at
//    3 blocks/CU (24 waves/CU max). Now 8 blocks x 4 waves = 32 waves/CU
//    (hardware max), 16 blocks/CU queued -> finer tail.
//  - Register-array preamble deleted: lane l loads only window (l&3)'s
//    center; __shfl_xor masks {1,2} give every lane the min/max box in
//    registers. No int c[24]/cxs[8] arrays -> __launch_bounds__(256,8)
//    (<=64 VGPR) is reachable without scratch spills (R1's suspected
//    silent killer of the occupancy gain).
//  - Worst-case-size LDS zero (constant trip count), overlaps preamble.

constexpr int L    = 512;
constexpr int W    = 9;
constexpr int W3   = W * W * W;          // 729
constexpr int HALF = W / 2;              // 4
constexpr int M    = 2 * L - 1;          // 1023 snake points
constexpr int G    = 4;                  // windows per block
constexpr int GW3  = G * W3;             // 2916 floats out per block
constexpr int BOXW = 2 * (G - 1) + W;    // 15 (worst-case box width)
constexpr int BOXN = BOXW * BOXW * BOXW; // 3375 floats = 13.5 KB
constexpr int THREADS = 256;

typedef float vfloat4 __attribute__((ext_vector_type(4)));

__global__ __launch_bounds__(THREADS, 8) void lattice_snake_kernel(
    const float* __restrict__ acids,   // [B, L]
    const float* __restrict__ mask,    // [B, L]
    const int*   __restrict__ idx,     // [B, L, 3]
    float*       __restrict__ out)     // [B, L, 9,9,9,1]
{
    const int blk = blockIdx.x;
    const int b   = blk >> 7;          // / (L/G) = 128 groups per batch
    const int g   = blk & 127;
    const int i0  = g * G;
    const int tid = threadIdx.x;

    const int*   idxb = idx   + (size_t)b * L * 3;
    const float* ab   = acids + (size_t)b * L;
    const float* mb   = mask  + (size_t)b * L;

    __shared__ float box[BOXN + 9];    // +pad for float4 zero overrun
    __shared__ int   win_base[G];      // per-window base linear offset in box

    // --- preamble: every lane loads ONE window center (lane&3), then
    // __shfl_xor {1,2} reduces min/max across each 4-lane group so every
    // thread holds the full bounding box in registers. ---
    const int w0 = tid & (G - 1);
    const int ii = i0 + w0;
    const int cx = 2 * idxb[3 * ii + 0] + 2 * (L - 1);
    const int cy = 2 * idxb[3 * ii + 1] + 2 * (L - 1);
    const int cz = 2 * idxb[3 * ii + 2] + 2 * (L - 1);
    int mnx = cx, mxx = cx, mny = cy, mxy = cy, mnz = cz, mxz = cz;
#pragma unroll
    for (int msk = 1; msk < G; msk <<= 1) {
        mnx = min(mnx, __shfl_xor(mnx, msk));
        mxx = max(mxx, __shfl_xor(mxx, msk));
        mny = min(mny, __shfl_xor(mny, msk));
        mxy = max(mxy, __shfl_xor(mxy, msk));
        mnz = min(mnz, __shfl_xor(mnz, msk));
        mxz = max(mxz, __shfl_xor(mxz, msk));
    }
    const int ox = mnx - HALF, oy = mny - HALF, oz = mnz - HALF;
    const int dxd = mxx - mnx + W;     // actual box dims, each <= 15
    // Odd y/z strides: kills even-stride LDS bank aliasing. Box is scratch;
    // extra never-read slots are harmless and padded dims stay <= 15.
    const int dyd = (mxy - mny + W) | 1;
    const int dzd = (mxz - mnz + W) | 1;
    const int dydzd = dyd * dzd;

    // Zero the worst-case box: constant trip count, no dependence on the
    // shuffle results -> overlaps the preamble loads.
    {
        const vfloat4 z = {0.0f, 0.0f, 0.0f, 0.0f};
#pragma unroll
        for (int k = tid * 4; k < BOXN; k += THREADS * 4)
            *(vfloat4*)&box[k] = z;
    }
    if (tid < G) {                     // tid==w0 for tid<4: own center held
        win_base[tid] = (cx - HALF - ox) * dydzd +
                        (cy - HALF - oy) * dzd +
                        (cz - HALF - oz);
    }
    __syncthreads();

    // --- scatter all snake points that land in the box ---
    for (int m = tid; m < M; m += THREADS) {
        int px, py, pz;
        float v;
        if (m < L) {
            px = 2 * idxb[3 * m + 0] + 2 * (L - 1);
            py = 2 * idxb[3 * m + 1] + 2 * (L - 1);
            pz = 2 * idxb[3 * m + 2] + 2 * (L - 1);
            v  = ab[m] * mb[m];
        } else {
            const int j = m - L;       // midpoint between residues j, j+1
            px = idxb[3 * j + 0] + idxb[3 * j + 3] + 2 * (L - 1);
            py = idxb[3 * j + 1] + idxb[3 * j + 4] + 2 * (L - 1);
            pz = idxb[3 * j + 2] + idxb[3 * j + 5] + 2 * (L - 1);
            v  = (ab[j] + ab[j + 1] + 1.0f) * mb[j + 1];
        }
        const int rx = px - ox, ry = py - oy, rz = pz - oz;
        if ((unsigned)rx < (unsigned)dxd && (unsigned)ry < (unsigned)dyd &&
            (unsigned)rz < (unsigned)dzd) {
            atomicAdd(&box[(rx * dyd + ry) * dzd + rz], v);
        }
    }
    __syncthreads();

    // --- emit: 4 windows = 2916 contiguous floats, float4 stores ---
    // Block base element index = (b*512 + i0)*729 with i0 % 4 == 0 and
    // 729 % 4 == 1 -> base % 4 == 0 -> 16B aligned.
    float* ob = out + ((size_t)b * L + i0) * W3;
    for (int e = tid * 4; e < GW3; e += THREADS * 4) {
        vfloat4 v4;
#pragma unroll
        for (int u = 0; u < 4; ++u) {
            const int ee = e + u;
            const int w  = ee / W3;          // window in group (magic-mul)
            const int k  = ee - w * W3;
            const int dx = k / 81;
            const int r  = k - dx * 81;
            const int dy = r / 9;
            const int dz = r - dy * 9;
            v4[u] = box[win_base[w] + dx * dydzd + dy * dzd + dz];
        }
        __builtin_nontemporal_store(v4, (vfloat4*)(ob + e));
    }
}

extern "C" void kernel_launch(void* const* d_in, const int* in_sizes, int n_in,
                              void* d_out, int out_size, void* d_ws, size_t ws_size,
                              hipStream_t stream) {
    const float* acids = (const float*)d_in[0];
    const float* mask  = (const float*)d_in[1];
    const int*   idx   = (const int*)d_in[2];
    float*       out   = (float*)d_out;

    const int B = in_sizes[0] / L;            // 32
    const int nblocks = B * (L / G);          // 4096 window groups

    lattice_snake_kernel<<<nblocks, THREADS, 0, stream>>>(acids, mask, idx, out);
}